// Round 20
// baseline (162.518 us; speedup 1.0000x reference)
//
#include <hip/hip_runtime.h>

typedef unsigned short u16;
typedef unsigned int u32;
typedef unsigned long long u64;
typedef __attribute__((ext_vector_type(8))) __bf16 b8;
typedef __attribute__((ext_vector_type(4))) float f32x4;

#define T_SEQ 2048
#define NB 4
#define NH 16
#define HD 64
#define CEMB 1024
#define M_ROWS (NB * T_SEQ)  // 8192
// 0.125 * log2(e): folds softmax scale AND exp->exp2 conversion into Q
#define Q_PRESCALE 0.18033688011112042f

__device__ __forceinline__ u16 f2bf(float f) {
  union { float f; unsigned int u; } v; v.f = f;
  unsigned int r = v.u + 0x7FFFu + ((v.u >> 16) & 1u);
  return (u16)(r >> 16);
}

__device__ __forceinline__ u32 pk2bf(float a, float b) {
  __bf16 x = (__bf16)a, y = (__bf16)b;
  return (u32)*(u16*)&x | ((u32)*(u16*)&y << 16);
}

__device__ __forceinline__ void gl_lds16(const u16* g, u16* l) {
  __builtin_amdgcn_global_load_lds(
      (const __attribute__((address_space(1))) unsigned int*)g,
      (__attribute__((address_space(3))) unsigned int*)l, 16, 0, 0);
}

#define BARRIER() __builtin_amdgcn_s_barrier()
#define LGKM0() do { asm volatile("s_waitcnt lgkmcnt(0)" ::: "memory"); \
                     __builtin_amdgcn_sched_barrier(0); } while (0)
#define VMCNT4() asm volatile("s_waitcnt vmcnt(4)" ::: "memory")
#define VMCNT2() asm volatile("s_waitcnt vmcnt(2)" ::: "memory")
#define VMCNT0() asm volatile("s_waitcnt vmcnt(0)" ::: "memory")

// ------------- fused pre-pass: x convert + both weight transposes -------------
__global__ __launch_bounds__(256) void k_prepass(const float* __restrict__ x,
                                                 u16* __restrict__ x_bf,
                                                 const float* __restrict__ W_attn,
                                                 u16* __restrict__ wattn_t,
                                                 const float* __restrict__ W_proj,
                                                 u16* __restrict__ wproj_t) {
  __shared__ u16 t[64][65];
  const int bidx = blockIdx.x;
  if (bidx < 2048) {
    const int n4 = (NB * T_SEQ * CEMB) / 4;
    const int stride = 2048 * 256;
    for (int i = bidx * 256 + threadIdx.x; i < n4; i += stride) {
      float4 v = ((const float4*)x)[i];
      ushort4 o;
      o.x = f2bf(v.x); o.y = f2bf(v.y); o.z = f2bf(v.z); o.w = f2bf(v.w);
      ((ushort4*)x_bf)[i] = o;
    }
  } else {
    const float* W; u16* Wt; int N, tloc;
    if (bidx < 2816) { W = W_attn; Wt = wattn_t; N = 3 * CEMB; tloc = bidx - 2048; }
    else             { W = W_proj; Wt = wproj_t; N = CEMB;     tloc = bidx - 2816; }
    const int K = CEMB;
    const int nx = N / 64;
    const int k0 = (tloc / nx) * 64, n0 = (tloc % nx) * 64;
    const int tx = threadIdx.x & 63, ty = threadIdx.x >> 6;
    for (int i = ty; i < 64; i += 4)
      t[i][tx] = f2bf(W[(size_t)(k0 + i) * N + n0 + tx]);
    __syncthreads();
    for (int i = ty; i < 64; i += 4)
      Wt[(size_t)(n0 + i) * K + k0 + tx] = t[tx][i];
  }
}

// ------------- 256xBN 8-phase bf16 GEMM body (shared-LDS-arena form) -----------
template <int MODE, int BNU>
__device__ __forceinline__ void gemm8_body(u16* sAbase, u16* sBbase, int bidx,
                                           const u16* __restrict__ A,
                                           const u16* __restrict__ Bt,
                                           const float* __restrict__ bias,
                                           u16* __restrict__ out_bf,
                                           float* __restrict__ out_f,
                                           u16* __restrict__ vt,
                                           int M, int N, int K, int mstripe) {
  constexpr int NI = BNU / 2;
  const int tid = threadIdx.x;
  const int lane = tid & 63;
  const int wid = tid >> 6;
  const int wm = wid >> 2;
  const int wn = wid & 3;
  const int fr = lane & 15;
  const int g = lane >> 4;

  const int xcd = bidx & 7;
  const int idx = bidx >> 3;
  const int mt = xcd * mstripe + (idx % mstripe);
  const int nt = idx / mstripe;
  const int row0 = mt * 256, col0 = nt * (BNU * 64);
  const int NT = K >> 6;

  const int kswz = ((lane & 7) ^ ((lane >> 3) & 7)) * 8;
  const u16* gA = A + (size_t)(row0 + wid * 8 + (lane >> 3)) * K + kswz;
  const u16* gB = Bt + (size_t)(col0 + wid * 8 + (lane >> 3)) * K + kswz;

#define SAB(buf) (sAbase + (buf) * 16384)
#define SBB(buf) (sBbase + (buf) * (BNU * 4096))
#define SGA(buf, T, u) gl_lds16(gA + (size_t)(u) * 64 * K + (size_t)(T) * 64, \
                                SAB(buf) + (u) * 4096 + wid * 512)
#define SGB(buf, T, u) gl_lds16(gB + (size_t)(u) * 64 * K + (size_t)(T) * 64, \
                                SBB(buf) + (u) * 4096 + wid * 512)
#define RDA(dst, rowe, ks)                                                     \
  { int row_ = (rowe);                                                         \
    dst = *(const b8*)&SAB(bufc)[row_ * 64 + ((((ks)*4 + g) ^ (row_ & 7)) << 3)]; }
#define RDB(dst, cole, ks)                                                     \
  { int col_ = (cole);                                                         \
    dst = *(const b8*)&SBB(bufc)[col_ * 64 + ((((ks)*4 + g) ^ (col_ & 7)) << 3)]; }

  f32x4 acc[8][BNU] = {};
  b8 aF[4][2], bF0[NI][2], bF1[NI][2];

#pragma unroll
  for (int u = 0; u < BNU; ++u) SGB(0, 0, u);
  SGA(0, 0, 0); SGA(0, 0, 2);
  SGA(0, 0, 1); SGA(0, 0, 3);
  SGA(1, 1, 0); SGA(1, 1, 2);
  VMCNT4();
  BARRIER();
  __builtin_amdgcn_sched_barrier(0);

#pragma unroll 2
  for (int T = 0; T < NT; ++T) {
    const int bufc = T & 1, bufn = bufc ^ 1;
    const bool st1 = (T + 1 < NT), st2 = (T + 2 < NT);

#pragma unroll
    for (int mi = 0; mi < 4; ++mi)
#pragma unroll
      for (int ks = 0; ks < 2; ++ks) RDA(aF[mi][ks], wm * 128 + mi * 16 + fr, ks);
#pragma unroll
    for (int ni = 0; ni < NI; ++ni)
#pragma unroll
      for (int ks = 0; ks < 2; ++ks) RDB(bF0[ni][ks], wn * (BNU * 16) + ni * 16 + fr, ks);
    if (st1) { SGB(bufn, T + 1, 0); SGB(bufn, T + 1, 1); }
    else VMCNT0();
    BARRIER(); LGKM0();
    __builtin_amdgcn_s_setprio(1);
#pragma unroll
    for (int mi = 0; mi < 4; ++mi)
#pragma unroll
      for (int ni = 0; ni < NI; ++ni)
#pragma unroll
        for (int ks = 0; ks < 2; ++ks)
          acc[mi][ni] = __builtin_amdgcn_mfma_f32_16x16x32_bf16(aF[mi][ks], bF0[ni][ks], acc[mi][ni], 0, 0, 0);
    __builtin_amdgcn_s_setprio(0);
    __builtin_amdgcn_sched_barrier(0);
    BARRIER();

#pragma unroll
    for (int ni = 0; ni < NI; ++ni)
#pragma unroll
      for (int ks = 0; ks < 2; ++ks) RDB(bF1[ni][ks], wn * (BNU * 16) + (NI + ni) * 16 + fr, ks);
    if (BNU == 4 && st1) { SGB(bufn, T + 1, 2); SGB(bufn, T + 1, 3); }
    if constexpr (BNU == 4) { VMCNT4(); } else { VMCNT2(); }
    BARRIER(); LGKM0();
    __builtin_amdgcn_s_setprio(1);
#pragma unroll
    for (int mi = 0; mi < 4; ++mi)
#pragma unroll
      for (int ni = 0; ni < NI; ++ni)
#pragma unroll
        for (int ks = 0; ks < 2; ++ks)
          acc[mi][NI + ni] = __builtin_amdgcn_mfma_f32_16x16x32_bf16(aF[mi][ks], bF1[ni][ks], acc[mi][NI + ni], 0, 0, 0);
    __builtin_amdgcn_s_setprio(0);
    __builtin_amdgcn_sched_barrier(0);
    BARRIER();

#pragma unroll
    for (int mi = 0; mi < 4; ++mi)
#pragma unroll
      for (int ks = 0; ks < 2; ++ks) RDA(aF[mi][ks], wm * 128 + 64 + mi * 16 + fr, ks);
    if (st2) { SGA(bufc, T + 2, 0); SGA(bufc, T + 2, 2); }
    BARRIER(); LGKM0();
    __builtin_amdgcn_s_setprio(1);
#pragma unroll
    for (int mi = 0; mi < 4; ++mi)
#pragma unroll
      for (int ni = 0; ni < NI; ++ni)
#pragma unroll
        for (int ks = 0; ks < 2; ++ks)
          acc[4 + mi][ni] = __builtin_amdgcn_mfma_f32_16x16x32_bf16(aF[mi][ks], bF0[ni][ks], acc[4 + mi][ni], 0, 0, 0);
    __builtin_amdgcn_s_setprio(0);
    __builtin_amdgcn_sched_barrier(0);
    BARRIER();

    if (st1) { SGA(bufn, T + 1, 1); SGA(bufn, T + 1, 3); }
    VMCNT4();
    BARRIER();
    __builtin_amdgcn_sched_barrier(0);
    __builtin_amdgcn_s_setprio(1);
#pragma unroll
    for (int mi = 0; mi < 4; ++mi)
#pragma unroll
      for (int ni = 0; ni < NI; ++ni)
#pragma unroll
        for (int ks = 0; ks < 2; ++ks)
          acc[4 + mi][NI + ni] = __builtin_amdgcn_mfma_f32_16x16x32_bf16(aF[mi][ks], bF1[ni][ks], acc[4 + mi][NI + ni], 0, 0, 0);
    __builtin_amdgcn_s_setprio(0);
    __builtin_amdgcn_sched_barrier(0);
    BARRIER();
  }
#undef SGA
#undef SGB
#undef RDA
#undef RDB

  const int fg = lane >> 4;
  if (MODE != 2) {
#pragma unroll
    for (int ni = 0; ni < BNU; ++ni) {
      int col = col0 + wn * (BNU * 16) + ni * 16 + fr;
      float bv = bias[col];
#pragma unroll
      for (int mi = 0; mi < 8; ++mi) {
#pragma unroll
        for (int r = 0; r < 4; ++r) {
          int row = row0 + wm * 128 + mi * 16 + fg * 4 + r;
          float v = acc[mi][ni][r] + bv;
          if (MODE == 0) {
            float sc = (col < CEMB) ? Q_PRESCALE : 1.0f;
            out_bf[(size_t)row * (2 * CEMB) + col] = f2bf(v * sc);
          } else {
            out_f[(size_t)row * N + col] = v;
          }
        }
      }
    }
  } else {
    // MODE 2: transpose 256(T) x 128(hd) tile through LDS, store vt coalesced.
    u16* st = sAbase;
    const int bq = row0 >> 11;
    const int t0g = row0 & (T_SEQ - 1);
#pragma unroll
    for (int pass = 0; pass < 2; ++pass) {
      __syncthreads();
      if ((wn >> 1) == pass) {
#pragma unroll
        for (int nn = 0; nn < BNU; ++nn) {
          const int hdl = (wn & 1) * 32 + nn * 16 + fr;
          const float bv = bias[col0 + pass * 64 + hdl];
#pragma unroll
          for (int mi = 0; mi < 8; ++mi) {
            const int tl = wm * 128 + mi * 16 + fg * 4;
#pragma unroll
            for (int rp = 0; rp < 2; ++rp) {
              u32 pk = pk2bf(acc[mi][nn][2 * rp] + bv, acc[mi][nn][2 * rp + 1] + bv);
              *(u32*)&st[hdl * 280 + tl + 2 * rp] = pk;
            }
          }
        }
      }
      __syncthreads();
      const int hd_r = tid >> 3;
      const int ck = tid & 7;
      u16* vrow = vt + ((size_t)(bq * (NH * HD) + col0 + pass * 64 + hd_r)) * T_SEQ + t0g;
#pragma unroll
      for (int j = 0; j < 4; ++j) {
        const int chunk = ck + 8 * j;
        f32x4 d = *(const f32x4*)&st[hd_r * 280 + chunk * 8];
        *(f32x4*)&vrow[chunk * 8] = d;
      }
    }
  }
#undef SAB
#undef SBB
}

// fused QK-GEMM (blocks 0..255) + V-GEMM (blocks 256..511) in one dispatch
__global__ __launch_bounds__(512, 2) void k_gemm_qkv(const u16* __restrict__ x_bf,
                                                     const u16* __restrict__ wattn_t,
                                                     const float* __restrict__ b_attn,
                                                     u16* __restrict__ qk_bf,
                                                     u16* __restrict__ vt) {
  __shared__ u16 smem[65536];
  if (blockIdx.x < 256) {
    gemm8_body<0, 4>(smem, smem + 32768, blockIdx.x,
                     x_bf, wattn_t, b_attn, qk_bf, nullptr, nullptr,
                     M_ROWS, 2 * CEMB, CEMB, 4);
  } else {
    gemm8_body<2, 2>(smem, smem + 32768, blockIdx.x - 256,
                     x_bf, wattn_t + 2048 * CEMB, b_attn + 2 * CEMB,
                     nullptr, nullptr, vt, M_ROWS, CEMB, CEMB, 4);
  }
}

// standalone GEMM2 (depends on attention output)
__global__ __launch_bounds__(512, 2) void k_gemm2(const u16* __restrict__ y_bf,
                                                  const u16* __restrict__ wproj_t,
                                                  const float* __restrict__ b_proj,
                                                  float* __restrict__ out) {
  __shared__ u16 smem[49152];
  gemm8_body<1, 2>(smem, smem + 32768, blockIdx.x,
                   y_bf, wproj_t, b_proj, nullptr, out, nullptr,
                   M_ROWS, CEMB, CEMB, 4);
}

// ------------- causal flash attention v9: 8-wave + counted-vmcnt staging (T4) -------
// R19 structure (512 blocks x 512 thr, 128-row q-tiles, uniform pairs, 48 KB LDS)
// with the draining __syncthreads replaced by the counted protocol:
//   top: STAGE(t+1); s_waitcnt vmcnt(2)   (own t-staging complete, t+1 in flight)
//        s_barrier                        (publish all waves' drains before reads)
//   ... compute ...
//        s_barrier                        (all reads of buf[cur] done before S(t+2))
// Staging latency hides under compute instead of serializing at a vmcnt(0) drain.
__global__ __launch_bounds__(512, 4) void k_attn(const u16* __restrict__ qk,
                                                 const u16* __restrict__ vtg,
                                                 u16* __restrict__ y) {
  __shared__ __align__(16) u16 kt_s[2][64 * 64];
  __shared__ __align__(16) u16 vt_s[2][64 * 64];
  __shared__ __align__(16) char pl_s[8][2048];

  const int lane = threadIdx.x & 63;
  const int wave = threadIdx.x >> 6;   // 0..7
  const int tid = threadIdx.x;
  const int g = lane >> 4, c = lane & 15;

  const int xcd = blockIdx.x & 7;
  const int idx = blockIdx.x >> 3;     // 0..63
  const int bh = xcd * 8 + (idx & 7);
  const int pr = idx >> 3;             // 0..7 -> tile pair (15-pr, pr)
  const int b = bh >> 4, h = bh & 15;

  char* plA = pl_s[wave] + c * 128;
  const int b3 = c >> 3;
  const int e2 = (c & 7) << 1;
  const int sb = g + b3 * 8;

  b8 ones_frag;
#pragma unroll
  for (int e = 0; e < 8; ++e) ones_frag[e] = (c == 0) ? (__bf16)1.0f : (__bf16)0.0f;

  const int srow = tid >> 3;           // 0..63
  const int scc = (tid & 7) ^ (srow & 7);
  const u16* ksrc0 = qk + ((size_t)(b * T_SEQ) + srow) * (2 * CEMB) + CEMB + h * HD + scc * 8;
  const u16* vsrc0 = vtg + ((size_t)(bh * HD) + srow) * T_SEQ + scc * 8;

#define STAGE(t, bb)                                                    \
  {                                                                     \
    gl_lds16(ksrc0 + (size_t)(t) * 64 * (2 * CEMB), &kt_s[bb][wave * 512]); \
    gl_lds16(vsrc0 + (t) * 64, &vt_s[bb][wave * 512]);                  \
  }

#pragma unroll 1
  for (int seg = 0; seg < 2; ++seg) {
    const int tt = seg ? pr : (15 - pr);   // 128-row tile index, 0..15
    const int qW = tt * 128 + wave * 16;   // this wave's 16 q rows

    const u16* qrow = qk + (size_t)(b * T_SEQ + qW + c) * (2 * CEMB) + h * HD + g * 8;
    const b8 qf0 = *(const b8*)qrow;
    const b8 qf1 = *(const b8*)(qrow + 32);

    float m = -3e38f;
    f32x4 o[4] = {};
    f32x4 o4 = {0.f, 0.f, 0.f, 0.f};

    const int ntt = 2 * tt + 2;
    int cur = 0;
    STAGE(0, 0);

    for (int t = 0; t < ntt; ++t) {
      // counted-vmcnt staging sync (T4): keep next tile's loads in flight
      if (t + 1 < ntt) { STAGE(t + 1, cur ^ 1); VMCNT2(); }
      else { VMCNT0(); }
      __builtin_amdgcn_sched_barrier(0);
      BARRIER();
      __builtin_amdgcn_sched_barrier(0);

      const int k0 = t * 64;
      const bool lastt = (t == ntt - 1);  // waves 0-3 idle; waves 4-7 diagonal
      const bool sndl = (t == ntt - 2);   // waves 0-3 diagonal; waves 4-7 full
      const u16* kt = kt_s[cur];
      const u16* vtl = vt_s[cur];

      const bool act = !(lastt && wave < 4);
      if (act) {
        const int nhi = sndl ? (wave < 4 ? wave : 3) : (lastt ? wave - 4 : 3);
        const bool dmask = (sndl && wave < 4) || (lastt && wave >= 4);

        // QK^T (swapped): s[n][r] = S[k=k0+n*16+g*4+r][q=c]
        f32x4 s[4] = {{0.f,0.f,0.f,0.f},{0.f,0.f,0.f,0.f},{0.f,0.f,0.f,0.f},{0.f,0.f,0.f,0.f}};
        __builtin_amdgcn_s_setprio(1);
#pragma unroll
        for (int n = 0; n < 4; ++n) {
          if (n <= nhi) {
            const b8 kf0 = *(const b8*)&kt[(n * 16 + c) * 64 + ((g ^ (c & 7)) << 3)];
            const b8 kf1 = *(const b8*)&kt[(n * 16 + c) * 64 + (((4 + g) ^ (c & 7)) << 3)];
            s[n] = __builtin_amdgcn_mfma_f32_16x16x32_bf16(kf0, qf0, s[n], 0, 0, 0);
            s[n] = __builtin_amdgcn_mfma_f32_16x16x32_bf16(kf1, qf1, s[n], 0, 0, 0);
          }
        }
        __builtin_amdgcn_s_setprio(0);

        // V fragments early: DS pipe overlaps the softmax VALU chain below
        b8 vb[2][4];
#pragma unroll
        for (int ks = 0; ks < 2; ++ks)
#pragma unroll
          for (int nt = 0; nt < 4; ++nt)
            vb[ks][nt] = *(const b8*)&vtl[(nt * 16 + c) * 64 + (((ks * 4 + g) ^ (c & 7)) << 3)];

        // causal mask (k > q) on the diagonal iteration (kills skipped n too)
        if (dmask) {
#pragma unroll
          for (int n = 0; n < 4; ++n)
#pragma unroll
            for (int r = 0; r < 4; ++r)
              if (k0 + n * 16 + g * 4 + r > qW + c) s[n][r] = -3e38f;
        }

        // row max: tree over 16 in-lane values + 2 cross-g shuffles
        float rm = fmaxf(fmaxf(fmaxf(s[0][0], s[0][1]), s[0][2]),
                         fmaxf(fmaxf(s[0][3], s[1][0]), s[1][1]));
        rm = fmaxf(rm, fmaxf(fmaxf(s[1][2], s[1][3]), s[2][0]));
        rm = fmaxf(rm, fmaxf(fmaxf(s[2][1], s[2][2]), s[2][3]));
        rm = fmaxf(rm, fmaxf(fmaxf(s[3][0], s[3][1]), fmaxf(s[3][2], s[3][3])));
        rm = fmaxf(rm, __shfl_xor(rm, 16));
        rm = fmaxf(rm, __shfl_xor(rm, 32));

        // defer-max (THR=8 in log2 units)
        if (!__all(rm <= m + 8.0f)) {
          float mn = fmaxf(m, rm);
          float al = __builtin_amdgcn_exp2f(m - mn);
          m = mn;
#pragma unroll
          for (int r = 0; r < 4; ++r) {
            int src = (lane & 48) + g * 4 + r;
            float a = __shfl(al, src);
#pragma unroll
            for (int nt = 0; nt < 4; ++nt) o[nt][r] *= a;
            o4[r] *= a;
          }
        }

        // P = exp2(s - m) -> packed bf16 -> conflict-free LDS slots
#pragma unroll
        for (int n = 0; n < 4; ++n) {
          u32 lo = pk2bf(__builtin_amdgcn_exp2f(s[n][0] - m),
                         __builtin_amdgcn_exp2f(s[n][1] - m));
          u32 hi = pk2bf(__builtin_amdgcn_exp2f(s[n][2] - m),
                         __builtin_amdgcn_exp2f(s[n][3] - m));
          *(u64*)(plA + ((((4 * n + sb) & 15) ^ e2) << 3)) = ((u64)hi << 32) | lo;
        }

        // PV: one 10-MFMA cluster; compiler emits precise lgkmcnt for P RAW.
        __builtin_amdgcn_s_setprio(1);
#pragma unroll
        for (int ks = 0; ks < 2; ++ks) {
          const b8 pa = *(const b8*)(plA + ((((ks * 8 + 2 * g + 8 * b3) & 15) ^ e2) << 3));
          o4 = __builtin_amdgcn_mfma_f32_16x16x32_bf16(pa, ones_frag, o4, 0, 0, 0);
#pragma unroll
          for (int nt = 0; nt < 4; ++nt)
            o[nt] = __builtin_amdgcn_mfma_f32_16x16x32_bf16(pa, vb[ks][nt], o[nt], 0, 0, 0);
        }
        __builtin_amdgcn_s_setprio(0);
      }

      // all reads of buf[cur] complete before any wave stages into it (t+2)
      __builtin_amdgcn_sched_barrier(0);
      BARRIER();
      cur ^= 1;
    }

    // segment epilogue: denominator in col 0 (lanes c==0 of each g-group)
#pragma unroll
    for (int r = 0; r < 4; ++r) {
      float lr = __shfl(o4[r], lane & 48);
      float inv = 1.0f / lr;
#pragma unroll
      for (int nt = 0; nt < 4; ++nt) {
        __bf16 ov = (__bf16)(o[nt][r] * inv);
        y[(size_t)(b * T_SEQ + qW + g * 4 + r) * CEMB + h * HD + nt * 16 + c] = *(u16*)&ov;
      }
    }
  }
#undef STAGE
}

extern "C" void kernel_launch(void* const* d_in, const int* in_sizes, int n_in,
                              void* d_out, int out_size, void* d_ws, size_t ws_size,
                              hipStream_t stream) {
  const float* x = (const float*)d_in[0];
  const float* W_attn = (const float*)d_in[1];
  const float* b_attn = (const float*)d_in[2];
  const float* W_proj = (const float*)d_in[3];
  const float* b_proj = (const float*)d_in[4];
  float* out = (float*)d_out;

  char* ws = (char*)d_ws;
  u16* x_bf    = (u16*)(ws);
  u16* wattn_t = (u16*)(ws + 16777216);
  u16* wproj_t = (u16*)(ws + 23068672);
  u16* qk_bf   = (u16*)(ws + 25165824);
  u16* vt      = (u16*)(ws + 58720256);
  u16* y_bf    = (u16*)(ws + 75497472);

  k_prepass<<<3072, 256, 0, stream>>>(x, x_bf, W_attn, wattn_t, W_proj, wproj_t);
  // fused QK-GEMM + V-GEMM: 512 blocks, V blocks backfill as QK blocks retire
  k_gemm_qkv<<<512, 512, 0, stream>>>(x_bf, wattn_t, b_attn, qk_bf, vt);
  // attention: 512 uniform blocks (34 KV-iters each) x 512 threads, 48 KB LDS
  k_attn<<<512, 512, 0, stream>>>(qk_bf, vt, y_bf);
  // GEMM2: M=8192, N=1024 -> 256 blocks = 1/CU
  k_gemm2<<<256, 512, 0, stream>>>(y_bf, wproj_t, b_proj, out);
}

// Round 21
// 161.683 us; speedup vs baseline: 1.0052x; 1.0052x over previous
//
#include <hip/hip_runtime.h>

typedef unsigned short u16;
typedef unsigned int u32;
typedef unsigned long long u64;
typedef __attribute__((ext_vector_type(8))) __bf16 b8;
typedef __attribute__((ext_vector_type(4))) float f32x4;

#define T_SEQ 2048
#define NB 4
#define NH 16
#define HD 64
#define CEMB 1024
#define M_ROWS (NB * T_SEQ)  // 8192
// 0.125 * log2(e): folds softmax scale AND exp->exp2 conversion into Q
#define Q_PRESCALE 0.18033688011112042f

__device__ __forceinline__ u16 f2bf(float f) {
  union { float f; unsigned int u; } v; v.f = f;
  unsigned int r = v.u + 0x7FFFu + ((v.u >> 16) & 1u);
  return (u16)(r >> 16);
}

__device__ __forceinline__ u32 pk2bf(float a, float b) {
  __bf16 x = (__bf16)a, y = (__bf16)b;
  return (u32)*(u16*)&x | ((u32)*(u16*)&y << 16);
}

__device__ __forceinline__ void gl_lds16(const u16* g, u16* l) {
  __builtin_amdgcn_global_load_lds(
      (const __attribute__((address_space(1))) unsigned int*)g,
      (__attribute__((address_space(3))) unsigned int*)l, 16, 0, 0);
}

#define BARRIER() __builtin_amdgcn_s_barrier()
#define LGKM0() do { asm volatile("s_waitcnt lgkmcnt(0)" ::: "memory"); \
                     __builtin_amdgcn_sched_barrier(0); } while (0)
#define VMCNT4() asm volatile("s_waitcnt vmcnt(4)" ::: "memory")
#define VMCNT2() asm volatile("s_waitcnt vmcnt(2)" ::: "memory")
#define VMCNT0() asm volatile("s_waitcnt vmcnt(0)" ::: "memory")

// ------------- fused pre-pass: x convert + both weight transposes -------------
__global__ __launch_bounds__(256) void k_prepass(const float* __restrict__ x,
                                                 u16* __restrict__ x_bf,
                                                 const float* __restrict__ W_attn,
                                                 u16* __restrict__ wattn_t,
                                                 const float* __restrict__ W_proj,
                                                 u16* __restrict__ wproj_t) {
  __shared__ u16 t[64][65];
  const int bidx = blockIdx.x;
  if (bidx < 2048) {
    const int n4 = (NB * T_SEQ * CEMB) / 4;
    const int stride = 2048 * 256;
    for (int i = bidx * 256 + threadIdx.x; i < n4; i += stride) {
      float4 v = ((const float4*)x)[i];
      ushort4 o;
      o.x = f2bf(v.x); o.y = f2bf(v.y); o.z = f2bf(v.z); o.w = f2bf(v.w);
      ((ushort4*)x_bf)[i] = o;
    }
  } else {
    const float* W; u16* Wt; int N, tloc;
    if (bidx < 2816) { W = W_attn; Wt = wattn_t; N = 3 * CEMB; tloc = bidx - 2048; }
    else             { W = W_proj; Wt = wproj_t; N = CEMB;     tloc = bidx - 2816; }
    const int K = CEMB;
    const int nx = N / 64;
    const int k0 = (tloc / nx) * 64, n0 = (tloc % nx) * 64;
    const int tx = threadIdx.x & 63, ty = threadIdx.x >> 6;
    for (int i = ty; i < 64; i += 4)
      t[i][tx] = f2bf(W[(size_t)(k0 + i) * N + n0 + tx]);
    __syncthreads();
    for (int i = ty; i < 64; i += 4)
      Wt[(size_t)(n0 + i) * K + k0 + tx] = t[tx][i];
  }
}

// ------------- 256xBN 8-phase bf16 GEMM body (shared-LDS-arena form) -----------
template <int MODE, int BNU>
__device__ __forceinline__ void gemm8_body(u16* sAbase, u16* sBbase, int bidx,
                                           const u16* __restrict__ A,
                                           const u16* __restrict__ Bt,
                                           const float* __restrict__ bias,
                                           u16* __restrict__ out_bf,
                                           float* __restrict__ out_f,
                                           u16* __restrict__ vt,
                                           int M, int N, int K, int mstripe) {
  constexpr int NI = BNU / 2;
  const int tid = threadIdx.x;
  const int lane = tid & 63;
  const int wid = tid >> 6;
  const int wm = wid >> 2;
  const int wn = wid & 3;
  const int fr = lane & 15;
  const int g = lane >> 4;

  const int xcd = bidx & 7;
  const int idx = bidx >> 3;
  const int mt = xcd * mstripe + (idx % mstripe);
  const int nt = idx / mstripe;
  const int row0 = mt * 256, col0 = nt * (BNU * 64);
  const int NT = K >> 6;

  const int kswz = ((lane & 7) ^ ((lane >> 3) & 7)) * 8;
  const u16* gA = A + (size_t)(row0 + wid * 8 + (lane >> 3)) * K + kswz;
  const u16* gB = Bt + (size_t)(col0 + wid * 8 + (lane >> 3)) * K + kswz;

#define SAB(buf) (sAbase + (buf) * 16384)
#define SBB(buf) (sBbase + (buf) * (BNU * 4096))
#define SGA(buf, T, u) gl_lds16(gA + (size_t)(u) * 64 * K + (size_t)(T) * 64, \
                                SAB(buf) + (u) * 4096 + wid * 512)
#define SGB(buf, T, u) gl_lds16(gB + (size_t)(u) * 64 * K + (size_t)(T) * 64, \
                                SBB(buf) + (u) * 4096 + wid * 512)
#define RDA(dst, rowe, ks)                                                     \
  { int row_ = (rowe);                                                         \
    dst = *(const b8*)&SAB(bufc)[row_ * 64 + ((((ks)*4 + g) ^ (row_ & 7)) << 3)]; }
#define RDB(dst, cole, ks)                                                     \
  { int col_ = (cole);                                                         \
    dst = *(const b8*)&SBB(bufc)[col_ * 64 + ((((ks)*4 + g) ^ (col_ & 7)) << 3)]; }

  f32x4 acc[8][BNU] = {};
  b8 aF[4][2], bF0[NI][2], bF1[NI][2];

#pragma unroll
  for (int u = 0; u < BNU; ++u) SGB(0, 0, u);
  SGA(0, 0, 0); SGA(0, 0, 2);
  SGA(0, 0, 1); SGA(0, 0, 3);
  SGA(1, 1, 0); SGA(1, 1, 2);
  VMCNT4();
  BARRIER();
  __builtin_amdgcn_sched_barrier(0);

#pragma unroll 2
  for (int T = 0; T < NT; ++T) {
    const int bufc = T & 1, bufn = bufc ^ 1;
    const bool st1 = (T + 1 < NT), st2 = (T + 2 < NT);

#pragma unroll
    for (int mi = 0; mi < 4; ++mi)
#pragma unroll
      for (int ks = 0; ks < 2; ++ks) RDA(aF[mi][ks], wm * 128 + mi * 16 + fr, ks);
#pragma unroll
    for (int ni = 0; ni < NI; ++ni)
#pragma unroll
      for (int ks = 0; ks < 2; ++ks) RDB(bF0[ni][ks], wn * (BNU * 16) + ni * 16 + fr, ks);
    if (st1) { SGB(bufn, T + 1, 0); SGB(bufn, T + 1, 1); }
    else VMCNT0();
    BARRIER(); LGKM0();
    __builtin_amdgcn_s_setprio(1);
#pragma unroll
    for (int mi = 0; mi < 4; ++mi)
#pragma unroll
      for (int ni = 0; ni < NI; ++ni)
#pragma unroll
        for (int ks = 0; ks < 2; ++ks)
          acc[mi][ni] = __builtin_amdgcn_mfma_f32_16x16x32_bf16(aF[mi][ks], bF0[ni][ks], acc[mi][ni], 0, 0, 0);
    __builtin_amdgcn_s_setprio(0);
    __builtin_amdgcn_sched_barrier(0);
    BARRIER();

#pragma unroll
    for (int ni = 0; ni < NI; ++ni)
#pragma unroll
      for (int ks = 0; ks < 2; ++ks) RDB(bF1[ni][ks], wn * (BNU * 16) + (NI + ni) * 16 + fr, ks);
    if (BNU == 4 && st1) { SGB(bufn, T + 1, 2); SGB(bufn, T + 1, 3); }
    if constexpr (BNU == 4) { VMCNT4(); } else { VMCNT2(); }
    BARRIER(); LGKM0();
    __builtin_amdgcn_s_setprio(1);
#pragma unroll
    for (int mi = 0; mi < 4; ++mi)
#pragma unroll
      for (int ni = 0; ni < NI; ++ni)
#pragma unroll
        for (int ks = 0; ks < 2; ++ks)
          acc[mi][NI + ni] = __builtin_amdgcn_mfma_f32_16x16x32_bf16(aF[mi][ks], bF1[ni][ks], acc[mi][NI + ni], 0, 0, 0);
    __builtin_amdgcn_s_setprio(0);
    __builtin_amdgcn_sched_barrier(0);
    BARRIER();

#pragma unroll
    for (int mi = 0; mi < 4; ++mi)
#pragma unroll
      for (int ks = 0; ks < 2; ++ks) RDA(aF[mi][ks], wm * 128 + 64 + mi * 16 + fr, ks);
    if (st2) { SGA(bufc, T + 2, 0); SGA(bufc, T + 2, 2); }
    BARRIER(); LGKM0();
    __builtin_amdgcn_s_setprio(1);
#pragma unroll
    for (int mi = 0; mi < 4; ++mi)
#pragma unroll
      for (int ni = 0; ni < NI; ++ni)
#pragma unroll
        for (int ks = 0; ks < 2; ++ks)
          acc[4 + mi][ni] = __builtin_amdgcn_mfma_f32_16x16x32_bf16(aF[mi][ks], bF0[ni][ks], acc[4 + mi][ni], 0, 0, 0);
    __builtin_amdgcn_s_setprio(0);
    __builtin_amdgcn_sched_barrier(0);
    BARRIER();

    if (st1) { SGA(bufn, T + 1, 1); SGA(bufn, T + 1, 3); }
    VMCNT4();
    BARRIER();
    __builtin_amdgcn_sched_barrier(0);
    __builtin_amdgcn_s_setprio(1);
#pragma unroll
    for (int mi = 0; mi < 4; ++mi)
#pragma unroll
      for (int ni = 0; ni < NI; ++ni)
#pragma unroll
        for (int ks = 0; ks < 2; ++ks)
          acc[4 + mi][NI + ni] = __builtin_amdgcn_mfma_f32_16x16x32_bf16(aF[mi][ks], bF1[ni][ks], acc[4 + mi][NI + ni], 0, 0, 0);
    __builtin_amdgcn_s_setprio(0);
    __builtin_amdgcn_sched_barrier(0);
    BARRIER();
  }
#undef SGA
#undef SGB
#undef RDA
#undef RDB

  const int fg = lane >> 4;
  if (MODE != 2) {
#pragma unroll
    for (int ni = 0; ni < BNU; ++ni) {
      int col = col0 + wn * (BNU * 16) + ni * 16 + fr;
      float bv = bias[col];
#pragma unroll
      for (int mi = 0; mi < 8; ++mi) {
#pragma unroll
        for (int r = 0; r < 4; ++r) {
          int row = row0 + wm * 128 + mi * 16 + fg * 4 + r;
          float v = acc[mi][ni][r] + bv;
          if (MODE == 0) {
            float sc = (col < CEMB) ? Q_PRESCALE : 1.0f;
            out_bf[(size_t)row * (2 * CEMB) + col] = f2bf(v * sc);
          } else {
            out_f[(size_t)row * N + col] = v;
          }
        }
      }
    }
  } else {
    // MODE 2: transpose 256(T) x 128(hd) tile through LDS, store vt coalesced.
    u16* st = sAbase;
    const int bq = row0 >> 11;
    const int t0g = row0 & (T_SEQ - 1);
#pragma unroll
    for (int pass = 0; pass < 2; ++pass) {
      __syncthreads();
      if ((wn >> 1) == pass) {
#pragma unroll
        for (int nn = 0; nn < BNU; ++nn) {
          const int hdl = (wn & 1) * 32 + nn * 16 + fr;
          const float bv = bias[col0 + pass * 64 + hdl];
#pragma unroll
          for (int mi = 0; mi < 8; ++mi) {
            const int tl = wm * 128 + mi * 16 + fg * 4;
#pragma unroll
            for (int rp = 0; rp < 2; ++rp) {
              u32 pk = pk2bf(acc[mi][nn][2 * rp] + bv, acc[mi][nn][2 * rp + 1] + bv);
              *(u32*)&st[hdl * 280 + tl + 2 * rp] = pk;
            }
          }
        }
      }
      __syncthreads();
      const int hd_r = tid >> 3;
      const int ck = tid & 7;
      u16* vrow = vt + ((size_t)(bq * (NH * HD) + col0 + pass * 64 + hd_r)) * T_SEQ + t0g;
#pragma unroll
      for (int j = 0; j < 4; ++j) {
        const int chunk = ck + 8 * j;
        f32x4 d = *(const f32x4*)&st[hd_r * 280 + chunk * 8];
        *(f32x4*)&vrow[chunk * 8] = d;
      }
    }
  }
#undef SAB
#undef SBB
}

// fused QK-GEMM (blocks 0..255) + V-GEMM (blocks 256..511) in one dispatch
__global__ __launch_bounds__(512, 2) void k_gemm_qkv(const u16* __restrict__ x_bf,
                                                     const u16* __restrict__ wattn_t,
                                                     const float* __restrict__ b_attn,
                                                     u16* __restrict__ qk_bf,
                                                     u16* __restrict__ vt) {
  __shared__ u16 smem[65536];
  if (blockIdx.x < 256) {
    gemm8_body<0, 4>(smem, smem + 32768, blockIdx.x,
                     x_bf, wattn_t, b_attn, qk_bf, nullptr, nullptr,
                     M_ROWS, 2 * CEMB, CEMB, 4);
  } else {
    gemm8_body<2, 2>(smem, smem + 32768, blockIdx.x - 256,
                     x_bf, wattn_t + 2048 * CEMB, b_attn + 2 * CEMB,
                     nullptr, nullptr, vt, M_ROWS, CEMB, CEMB, 4);
  }
}

// standalone GEMM2 (depends on attention output)
__global__ __launch_bounds__(512, 2) void k_gemm2(const u16* __restrict__ y_bf,
                                                  const u16* __restrict__ wproj_t,
                                                  const float* __restrict__ b_proj,
                                                  float* __restrict__ out) {
  __shared__ u16 smem[49152];
  gemm8_body<1, 2>(smem, smem + 32768, blockIdx.x,
                   y_bf, wproj_t, b_proj, nullptr, out, nullptr,
                   M_ROWS, CEMB, CEMB, 4);
}

// ------------- causal flash attention v8 (best measured): 8-wave, 128-row tiles -----
// 512 blocks x 512 thr (8 waves x 16 q rows = 128-row tiles). Block (bh, pr) runs
// tiles 15-pr then pr: (2(15-pr)+2) + (2pr+2) = 34 KV-iters for EVERY block.
// K/V staged with ONE gl_lds16 per wave each (512 threads cover all 64 rows/call);
// staging amortizes over 8 waves. LDS = 2x8K + 2x8V + 16P = 48 KB -> 2 blocks/CU,
// 16 waves/CU. Causal edge: iter ntt-2 -> waves 0-3 diagonal; iter ntt-1 -> waves
// 0-3 idle (guarded; barriers outside guard), waves 4-7 diagonal.
__global__ __launch_bounds__(512, 4) void k_attn(const u16* __restrict__ qk,
                                                 const u16* __restrict__ vtg,
                                                 u16* __restrict__ y) {
  __shared__ __align__(16) u16 kt_s[2][64 * 64];
  __shared__ __align__(16) u16 vt_s[2][64 * 64];
  __shared__ __align__(16) char pl_s[8][2048];

  const int lane = threadIdx.x & 63;
  const int wave = threadIdx.x >> 6;   // 0..7
  const int tid = threadIdx.x;
  const int g = lane >> 4, c = lane & 15;

  // 512 blocks = 8 xcd x (8 bh_local x 8 pr): heads pinned to XCDs (L2 KV reuse)
  const int xcd = blockIdx.x & 7;
  const int idx = blockIdx.x >> 3;     // 0..63
  const int bh = xcd * 8 + (idx & 7);
  const int pr = idx >> 3;             // 0..7 -> tile pair (15-pr, pr)
  const int b = bh >> 4, h = bh & 15;

  char* plA = pl_s[wave] + c * 128;
  const int b3 = c >> 3;
  const int e2 = (c & 7) << 1;
  const int sb = g + b3 * 8;

  b8 ones_frag;
#pragma unroll
  for (int e = 0; e < 8; ++e) ones_frag[e] = (c == 0) ? (__bf16)1.0f : (__bf16)0.0f;

  // staging: 512 threads cover all 64 rows in one call; wave w writes rows w*8..w*8+7
  const int srow = tid >> 3;           // 0..63
  const int scc = (tid & 7) ^ (srow & 7);
  const u16* ksrc0 = qk + ((size_t)(b * T_SEQ) + srow) * (2 * CEMB) + CEMB + h * HD + scc * 8;
  const u16* vsrc0 = vtg + ((size_t)(bh * HD) + srow) * T_SEQ + scc * 8;

#define STAGE(t, bb)                                                    \
  {                                                                     \
    gl_lds16(ksrc0 + (size_t)(t) * 64 * (2 * CEMB), &kt_s[bb][wave * 512]); \
    gl_lds16(vsrc0 + (t) * 64, &vt_s[bb][wave * 512]);                  \
  }

#pragma unroll 1
  for (int seg = 0; seg < 2; ++seg) {
    const int tt = seg ? pr : (15 - pr);   // 128-row tile index, 0..15
    const int qW = tt * 128 + wave * 16;   // this wave's 16 q rows

    const u16* qrow = qk + (size_t)(b * T_SEQ + qW + c) * (2 * CEMB) + h * HD + g * 8;
    const b8 qf0 = *(const b8*)qrow;
    const b8 qf1 = *(const b8*)(qrow + 32);

    float m = -3e38f;
    f32x4 o[4] = {};
    f32x4 o4 = {0.f, 0.f, 0.f, 0.f};

    const int ntt = 2 * tt + 2;
    int cur = 0;
    STAGE(0, 0);
    __syncthreads();

    for (int t = 0; t < ntt; ++t) {
      if (t + 1 < ntt) STAGE(t + 1, cur ^ 1);
      const int k0 = t * 64;
      const bool lastt = (t == ntt - 1);  // waves 0-3 idle; waves 4-7 diagonal
      const bool sndl = (t == ntt - 2);   // waves 0-3 diagonal; waves 4-7 full
      const u16* kt = kt_s[cur];
      const u16* vtl = vt_s[cur];

      const bool act = !(lastt && wave < 4);
      if (act) {
        // subtile cap: diag waves compute only n <= boundary
        const int nhi = sndl ? (wave < 4 ? wave : 3) : (lastt ? wave - 4 : 3);
        const bool dmask = (sndl && wave < 4) || (lastt && wave >= 4);

        // QK^T (swapped): s[n][r] = S[k=k0+n*16+g*4+r][q=c]
        f32x4 s[4] = {{0.f,0.f,0.f,0.f},{0.f,0.f,0.f,0.f},{0.f,0.f,0.f,0.f},{0.f,0.f,0.f,0.f}};
        __builtin_amdgcn_s_setprio(1);
#pragma unroll
        for (int n = 0; n < 4; ++n) {
          if (n <= nhi) {
            const b8 kf0 = *(const b8*)&kt[(n * 16 + c) * 64 + ((g ^ (c & 7)) << 3)];
            const b8 kf1 = *(const b8*)&kt[(n * 16 + c) * 64 + (((4 + g) ^ (c & 7)) << 3)];
            s[n] = __builtin_amdgcn_mfma_f32_16x16x32_bf16(kf0, qf0, s[n], 0, 0, 0);
            s[n] = __builtin_amdgcn_mfma_f32_16x16x32_bf16(kf1, qf1, s[n], 0, 0, 0);
          }
        }
        __builtin_amdgcn_s_setprio(0);

        // V fragments early: DS pipe overlaps the softmax VALU chain below
        b8 vb[2][4];
#pragma unroll
        for (int ks = 0; ks < 2; ++ks)
#pragma unroll
          for (int nt = 0; nt < 4; ++nt)
            vb[ks][nt] = *(const b8*)&vtl[(nt * 16 + c) * 64 + (((ks * 4 + g) ^ (c & 7)) << 3)];

        // causal mask (k > q) on the diagonal iteration (kills skipped n too)
        if (dmask) {
#pragma unroll
          for (int n = 0; n < 4; ++n)
#pragma unroll
            for (int r = 0; r < 4; ++r)
              if (k0 + n * 16 + g * 4 + r > qW + c) s[n][r] = -3e38f;
        }

        // row max: tree over 16 in-lane values + 2 cross-g shuffles
        float rm = fmaxf(fmaxf(fmaxf(s[0][0], s[0][1]), s[0][2]),
                         fmaxf(fmaxf(s[0][3], s[1][0]), s[1][1]));
        rm = fmaxf(rm, fmaxf(fmaxf(s[1][2], s[1][3]), s[2][0]));
        rm = fmaxf(rm, fmaxf(fmaxf(s[2][1], s[2][2]), s[2][3]));
        rm = fmaxf(rm, fmaxf(fmaxf(s[3][0], s[3][1]), fmaxf(s[3][2], s[3][3])));
        rm = fmaxf(rm, __shfl_xor(rm, 16));
        rm = fmaxf(rm, __shfl_xor(rm, 32));

        // defer-max (THR=8 in log2 units)
        if (!__all(rm <= m + 8.0f)) {
          float mn = fmaxf(m, rm);
          float al = __builtin_amdgcn_exp2f(m - mn);
          m = mn;
#pragma unroll
          for (int r = 0; r < 4; ++r) {
            int src = (lane & 48) + g * 4 + r;
            float a = __shfl(al, src);
#pragma unroll
            for (int nt = 0; nt < 4; ++nt) o[nt][r] *= a;
            o4[r] *= a;
          }
        }

        // P = exp2(s - m) -> packed bf16 -> conflict-free LDS slots
#pragma unroll
        for (int n = 0; n < 4; ++n) {
          u32 lo = pk2bf(__builtin_amdgcn_exp2f(s[n][0] - m),
                         __builtin_amdgcn_exp2f(s[n][1] - m));
          u32 hi = pk2bf(__builtin_amdgcn_exp2f(s[n][2] - m),
                         __builtin_amdgcn_exp2f(s[n][3] - m));
          *(u64*)(plA + ((((4 * n + sb) & 15) ^ e2) << 3)) = ((u64)hi << 32) | lo;
        }

        // PV: one 10-MFMA cluster; compiler emits precise lgkmcnt for P RAW.
        __builtin_amdgcn_s_setprio(1);
#pragma unroll
        for (int ks = 0; ks < 2; ++ks) {
          const b8 pa = *(const b8*)(plA + ((((ks * 8 + 2 * g + 8 * b3) & 15) ^ e2) << 3));
          o4 = __builtin_amdgcn_mfma_f32_16x16x32_bf16(pa, ones_frag, o4, 0, 0, 0);
#pragma unroll
          for (int nt = 0; nt < 4; ++nt)
            o[nt] = __builtin_amdgcn_mfma_f32_16x16x32_bf16(pa, vb[ks][nt], o[nt], 0, 0, 0);
        }
        __builtin_amdgcn_s_setprio(0);
      }

      __syncthreads();
      cur ^= 1;
    }

    // segment epilogue: denominator in col 0 (lanes c==0 of each g-group)
#pragma unroll
    for (int r = 0; r < 4; ++r) {
      float lr = __shfl(o4[r], lane & 48);
      float inv = 1.0f / lr;
#pragma unroll
      for (int nt = 0; nt < 4; ++nt) {
        __bf16 ov = (__bf16)(o[nt][r] * inv);
        y[(size_t)(b * T_SEQ + qW + g * 4 + r) * CEMB + h * HD + nt * 16 + c] = *(u16*)&ov;
      }
    }
  }
#undef STAGE
}

extern "C" void kernel_launch(void* const* d_in, const int* in_sizes, int n_in,
                              void* d_out, int out_size, void* d_ws, size_t ws_size,
                              hipStream_t stream) {
  const float* x = (const float*)d_in[0];
  const float* W_attn = (const float*)d_in[1];
  const float* b_attn = (const float*)d_in[2];
  const float* W_proj = (const float*)d_in[3];
  const float* b_proj = (const float*)d_in[4];
  float* out = (float*)d_out;

  char* ws = (char*)d_ws;
  u16* x_bf    = (u16*)(ws);
  u16* wattn_t = (u16*)(ws + 16777216);
  u16* wproj_t = (u16*)(ws + 23068672);
  u16* qk_bf   = (u16*)(ws + 25165824);
  u16* vt      = (u16*)(ws + 58720256);
  u16* y_bf    = (u16*)(ws + 75497472);

  k_prepass<<<3072, 256, 0, stream>>>(x, x_bf, W_attn, wattn_t, W_proj, wproj_t);
  // fused QK-GEMM + V-GEMM: 512 blocks, V blocks backfill as QK blocks retire
  k_gemm_qkv<<<512, 512, 0, stream>>>(x_bf, wattn_t, b_attn, qk_bf, vt);
  // attention: 512 uniform blocks (34 KV-iters each) x 512 threads, 48 KB LDS
  k_attn<<<512, 512, 0, stream>>>(qk_bf, vt, y_bf);
  // GEMM2: M=8192, N=1024 -> 256 blocks = 1/CU
  k_gemm2<<<256, 512, 0, stream>>>(y_bf, wproj_t, b_proj, out);
}